// Round 9
// baseline (529.901 us; speedup 1.0000x reference)
//
#include <hip/hip_runtime.h>
#include <hip/hip_bf16.h>

// v9: paired-feature (dword) gathers in both agg kernels — agg1: 2 nodes/wave (32 lanes,
// features 2g/2g+1 per lane), final: 4 nodes/wave (16 lanes). Same bytes, half the VMEM
// instructions, 2x node parallelism. Epilogues restructured with chain order preserved
// exactly (P0+P1 split in agg1; sequential k in final) -> bit-identical numerics.
// v8's neutral 2-level pipeline reverted to simple 8-deep batches.

#define N_NODES 100000
#define N_EDGES 3200000
#define F_IN    128
#define H1F     64
#define H2F     32
#define NCLS    32
#define SCAN_BLOCK 1024
#define SCAN_CHUNKS ((N_NODES + SCAN_BLOCK - 1) / SCAN_BLOCK)   // 98
#define NTIL2 (N_NODES / 32)                                    // 3125 gemm tiles (32 nodes)
#define NCNT2 ((N_EDGES + 2048 - 1) / 2048)                     // 1563 count blocks (8 e/thr)
#define NFRONT (NTIL2 + NCNT2)                                  // 4688

typedef __attribute__((ext_vector_type(8))) short bf16x8;
typedef __attribute__((ext_vector_type(4))) float f32x4;

static __device__ __forceinline__ float b2f(__hip_bfloat16 v) {
    return __bfloat162float(v);
}
static __device__ __forceinline__ float us2f(unsigned short u) {
    return __uint_as_float(((unsigned)u) << 16);
}
static __device__ __forceinline__ float lo2f(unsigned u) {
    return __uint_as_float((u & 0xFFFFu) << 16);
}
static __device__ __forceinline__ float hi2f(unsigned u) {
    return __uint_as_float(u & 0xFFFF0000u);
}
static __device__ __forceinline__ unsigned short f2us(float f) {
    __hip_bfloat16 h = __float2bfloat16(f);
    return *(unsigned short*)&h;
}
static __device__ __forceinline__ float ld(const void* p, size_t i, int isbf) {
    return isbf ? b2f(((const __hip_bfloat16*)p)[i]) : ((const float*)p)[i];
}

// flags[0] = edge_index is int64 ; flags[1] = float tensors are bf16

// ---------------- init: zero deg + detect flags ----------------
__global__ void k_init(const void* xbuf, const void* eibuf, int* flags,
                       int* __restrict__ deg) {
    int t = blockIdx.x * blockDim.x + threadIdx.x;
    if (t < N_NODES) deg[t] = 0;
    if (blockIdx.x == 0 && threadIdx.x == 0) {
        const unsigned* ew = (const unsigned*)eibuf;
        int z = 0;
        for (int k = 0; k < 256; ++k) z += (ew[2 * k + 1] == 0u) ? 1 : 0;
        flags[0] = (z >= 200) ? 1 : 0;
        const unsigned* xw = (const unsigned*)xbuf;
        int inr = 0;
        for (int k = 0; k < 256; ++k) {
            unsigned fb = (xw[k] & 0xFFFFu) << 16;
            float a = fabsf(__uint_as_float(fb));
            inr += (a >= 1e-4f && a <= 20.0f) ? 1 : 0;
        }
        flags[1] = (inr >= 160) ? 1 : 0;
    }
}

// ---------------- FUSED front-end: gemm1 blocks interleaved with count blocks ----------
// blk%3==0 -> histogram+rank block (1563, 8 edges/thread)
// else     -> gemm1 tile block     (3125, 32 nodes: 8 nodes/wave, x via uniform s_load)
// Proven config (rounds 3/7/8): ~147us — count's atomic latency hides under gemm.
__global__ void __launch_bounds__(256)
k_front(const void* __restrict__ x, const void* __restrict__ W1,
        const int* __restrict__ ei,
        int* __restrict__ deg, int* __restrict__ aux,
        unsigned short* __restrict__ h1, const int* __restrict__ flags) {
    int blk = blockIdx.x, tid = threadIdx.x;

    if (blk % 3 == 0) {
        // -------- histogram + per-edge rank, 8 edges/thread --------
        int t = (blk / 3) * 256 + tid;
        int e0 = t * 8;
        if (e0 >= N_EDGES) return;
        int d[8];
        if (flags[0]) {
            const int4* p = (const int4*)(ei + 2 * (size_t)(N_EDGES + e0));
            int4 a = p[0], b = p[1], c = p[2], g = p[3];
            d[0] = a.x; d[1] = a.z; d[2] = b.x; d[3] = b.z;
            d[4] = c.x; d[5] = c.z; d[6] = g.x; d[7] = g.z;
        } else {
            const int4* p = (const int4*)(ei + (size_t)N_EDGES + e0);
            int4 a = p[0], b = p[1];
            d[0] = a.x; d[1] = a.y; d[2] = a.z; d[3] = a.w;
            d[4] = b.x; d[5] = b.y; d[6] = b.z; d[7] = b.w;
        }
        int r[8];
#pragma unroll
        for (int j = 0; j < 8; ++j)
            r[j] = ((unsigned)d[j] < N_NODES) ? atomicAdd(&deg[d[j]], 1) : 0;
        *(int4*)(aux + e0)     = make_int4(r[0], r[1], r[2], r[3]);
        *(int4*)(aux + e0 + 4) = make_int4(r[4], r[5], r[6], r[7]);
        return;
    }

    // -------- gemm1 tile: 32 nodes/block, 8 nodes/wave --------
    int tile = blk - blk / 3 - 1;                       // 0..3124, exact bijection
    int isbf = flags[1];
    int wave = __builtin_amdgcn_readfirstlane(tid >> 6);
    int lane = tid & 63;
    size_t nbase = (size_t)tile * 32 + (size_t)wave * 8;

    float acc[8];
#pragma unroll
    for (int i = 0; i < 8; ++i) acc[i] = 0.f;

    if (isbf) {
        const unsigned short* w  = (const unsigned short*)W1;
        const unsigned short* xp = (const unsigned short*)x;
#pragma unroll 4
        for (int k2 = 0; k2 < 64; ++k2) {
            float wa = us2f(w[(2 * k2) * H1F + lane]);
            float wb = us2f(w[(2 * k2 + 1) * H1F + lane]);
#pragma unroll
            for (int i = 0; i < 8; ++i) {
                float xa = us2f(xp[(nbase + i) * F_IN + 2 * k2]);
                float xb = us2f(xp[(nbase + i) * F_IN + 2 * k2 + 1]);
                acc[i] += xa * wa;
                acc[i] += xb * wb;
            }
        }
    } else {
        const float* w  = (const float*)W1;
        const float* xp = (const float*)x;
#pragma unroll 4
        for (int k2 = 0; k2 < 64; ++k2) {
            float wa = w[(2 * k2) * H1F + lane];
            float wb = w[(2 * k2 + 1) * H1F + lane];
#pragma unroll
            for (int i = 0; i < 8; ++i) {
                float xa = xp[(nbase + i) * F_IN + 2 * k2];
                float xb = xp[(nbase + i) * F_IN + 2 * k2 + 1];
                acc[i] += xa * wa;
                acc[i] += xb * wb;
            }
        }
    }

#pragma unroll
    for (int i = 0; i < 8; ++i)
        h1[(nbase + i) * H1F + lane] = f2us(acc[i]);
}

__global__ void k_scanA(const int* __restrict__ deg, int* __restrict__ partial,
                        float* __restrict__ dinv) {
    __shared__ int red[16];
    int b = blockIdx.x, t = threadIdx.x;
    int i = b * SCAN_BLOCK + t;
    int v = (i < N_NODES) ? deg[i] : 0;
    if (i < N_NODES) dinv[i] = rsqrtf((float)v + 1.0f);  // +1 self-loop (fused k_dinv)
    for (int off = 32; off; off >>= 1) v += __shfl_down(v, off, 64);
    if ((t & 63) == 0) red[t >> 6] = v;
    __syncthreads();
    if (t == 0) {
        int s = 0;
        for (int k = 0; k < 16; ++k) s += red[k];
        partial[b] = s;
    }
}

// scanC with scanB folded in: each block computes its own chunk offset by a parallel
// reduction of partial[0..b-1] (<=98 ints), then does the intra-chunk scan.
__global__ void k_scanC(const int* __restrict__ deg, const int* __restrict__ partial,
                        int* __restrict__ rowptr) {
    __shared__ int wsum[16];
    __shared__ int red[16];
    int b = blockIdx.x, t = threadIdx.x, lane = t & 63, w = t >> 6;
    int i = b * SCAN_BLOCK + t;
    int c = (t < SCAN_CHUNKS && t < b) ? partial[t] : 0;
    for (int off = 32; off; off >>= 1) c += __shfl_down(c, off, 64);
    if (lane == 0) red[w] = c;
    int v = (i < N_NODES) ? deg[i] : 0;
    for (int off = 1; off < 64; off <<= 1) {
        int u = __shfl_up(v, off, 64);
        if (lane >= off) v += u;
    }
    if (lane == 63) wsum[w] = v;
    __syncthreads();
    if (t == 0) {
        int run = 0;
        for (int k = 0; k < 16; ++k) { int s = wsum[k]; wsum[k] = run; run += s; }
        int sc = 0;
        for (int k = 0; k < 16; ++k) sc += red[k];
        red[0] = sc;                                    // chunk offset broadcast
    }
    __syncthreads();
    int incl = v + wsum[w] + red[0];
    if (i < N_NODES) rowptr[i + 1] = incl;
    if (b == 0 && t == 0) rowptr[0] = 0;
}

// atomic-free CSR fill using precomputed ranks; 8 edges/thread, batched rowptr gathers
__global__ void __launch_bounds__(256)
k_scatter(const int* __restrict__ ei, const int* __restrict__ aux,
          const int* __restrict__ rowptr, int* __restrict__ csr,
          const int* __restrict__ flags) {
    int t = blockIdx.x * blockDim.x + threadIdx.x;
    int e0 = t * 8;
    if (e0 >= N_EDGES) return;
    int s[8], d[8];
    if (flags[0]) {
        const int4* ps = (const int4*)(ei + 2 * (size_t)e0);
#pragma unroll
        for (int q = 0; q < 4; ++q) {
            int4 a = ps[q];
            s[2 * q] = a.x; s[2 * q + 1] = a.z;
        }
        const int4* pd = (const int4*)(ei + 2 * (size_t)(N_EDGES + e0));
#pragma unroll
        for (int q = 0; q < 4; ++q) {
            int4 c = pd[q];
            d[2 * q] = c.x; d[2 * q + 1] = c.z;
        }
    } else {
        const int4* ps = (const int4*)(ei + (size_t)e0);
#pragma unroll
        for (int q = 0; q < 2; ++q) {
            int4 a = ps[q];
            s[4 * q] = a.x; s[4 * q + 1] = a.y; s[4 * q + 2] = a.z; s[4 * q + 3] = a.w;
        }
        const int4* pd = (const int4*)(ei + (size_t)N_EDGES + e0);
#pragma unroll
        for (int q = 0; q < 2; ++q) {
            int4 c = pd[q];
            d[4 * q] = c.x; d[4 * q + 1] = c.y; d[4 * q + 2] = c.z; d[4 * q + 3] = c.w;
        }
    }
    int a8[8];
    {
        int4 av0 = *(const int4*)(aux + e0);
        int4 av1 = *(const int4*)(aux + e0 + 4);
        a8[0] = av0.x; a8[1] = av0.y; a8[2] = av0.z; a8[3] = av0.w;
        a8[4] = av1.x; a8[5] = av1.y; a8[6] = av1.z; a8[7] = av1.w;
    }
    int rp[8];
#pragma unroll
    for (int j = 0; j < 8; ++j) {
        bool ok = (unsigned)s[j] < N_NODES && (unsigned)d[j] < N_NODES;
        rp[j] = ok ? rowptr[d[j]] : -1;
    }
#pragma unroll
    for (int j = 0; j < 8; ++j) {
        if (rp[j] >= 0) csr[rp[j] + a8[j]] = s[j];
    }
}

// ---------------- fused agg1 + bias/ReLU + GEMM2 -> h2(bf16) ; HALF-WAVE per node -------
// 32 lanes/node; lane g holds features 2g,2g+1 (dword gathers). Per-feature FMA chains
// keep exact edge order. GEMM2 epilogue: P0 (k=0..31 asc) + P1 (k=32..63 asc) — matches
// the original two-half-chain association exactly.
__global__ void __launch_bounds__(256)
k_agg1gemm2(const unsigned short* __restrict__ h1,
            const float* __restrict__ dinv,
            const int* __restrict__ rowptr, const int* __restrict__ csr,
            const void* __restrict__ b1, const void* __restrict__ W2,
            unsigned short* __restrict__ h2, const int* __restrict__ flags) {
    int tid = blockIdx.x * blockDim.x + threadIdx.x;
    int n = tid >> 5;
    int g = threadIdx.x & 31;                           // feature pair index
    if (n >= N_NODES) return;
    int beg = rowptr[n], end = rowptr[n + 1];
    float dn = dinv[n];
    const unsigned* h1w = (const unsigned*)h1;
    unsigned su = h1w[(size_t)n * 32 + g];
    float ax = dn * lo2f(su);                           // feature 2g chain
    float ay = dn * hi2f(su);                           // feature 2g+1 chain
    int e = beg;
    for (; e + 7 < end; e += 8) {
        int s0 = csr[e],     s1 = csr[e + 1], s2 = csr[e + 2], s3 = csr[e + 3];
        int s4 = csr[e + 4], s5 = csr[e + 5], s6 = csr[e + 6], s7 = csr[e + 7];
        float w0 = dinv[s0], w1 = dinv[s1], w2 = dinv[s2], w3 = dinv[s3];
        float w4 = dinv[s4], w5 = dinv[s5], w6 = dinv[s6], w7 = dinv[s7];
        unsigned u0 = h1w[(size_t)s0 * 32 + g];
        unsigned u1 = h1w[(size_t)s1 * 32 + g];
        unsigned u2 = h1w[(size_t)s2 * 32 + g];
        unsigned u3 = h1w[(size_t)s3 * 32 + g];
        unsigned u4 = h1w[(size_t)s4 * 32 + g];
        unsigned u5 = h1w[(size_t)s5 * 32 + g];
        unsigned u6 = h1w[(size_t)s6 * 32 + g];
        unsigned u7 = h1w[(size_t)s7 * 32 + g];
        ax += w0 * lo2f(u0); ay += w0 * hi2f(u0);
        ax += w1 * lo2f(u1); ay += w1 * hi2f(u1);
        ax += w2 * lo2f(u2); ay += w2 * hi2f(u2);
        ax += w3 * lo2f(u3); ay += w3 * hi2f(u3);
        ax += w4 * lo2f(u4); ay += w4 * hi2f(u4);
        ax += w5 * lo2f(u5); ay += w5 * hi2f(u5);
        ax += w6 * lo2f(u6); ay += w6 * hi2f(u6);
        ax += w7 * lo2f(u7); ay += w7 * hi2f(u7);
    }
    for (; e + 3 < end; e += 4) {
        int s0 = csr[e], s1 = csr[e + 1], s2 = csr[e + 2], s3 = csr[e + 3];
        float w0 = dinv[s0], w1 = dinv[s1], w2 = dinv[s2], w3 = dinv[s3];
        unsigned u0 = h1w[(size_t)s0 * 32 + g];
        unsigned u1 = h1w[(size_t)s1 * 32 + g];
        unsigned u2 = h1w[(size_t)s2 * 32 + g];
        unsigned u3 = h1w[(size_t)s3 * 32 + g];
        ax += w0 * lo2f(u0); ay += w0 * hi2f(u0);
        ax += w1 * lo2f(u1); ay += w1 * hi2f(u1);
        ax += w2 * lo2f(u2); ay += w2 * hi2f(u2);
        ax += w3 * lo2f(u3); ay += w3 * hi2f(u3);
    }
    for (; e < end; ++e) {
        int s = csr[e];
        float w = dinv[s];
        unsigned u = h1w[(size_t)s * 32 + g];
        ax += w * lo2f(u); ay += w * hi2f(u);
    }
    ax *= dn; ay *= dn;                                 // agg1[n][2g], [2g+1]
    int isbf = flags[1];
    float vx = fmaxf(ax + ld(b1, 2 * g, isbf), 0.f);
    float vy = fmaxf(ay + ld(b1, 2 * g + 1, isbf), 0.f);
    // GEMM2: output feature f = g. P0 = k 0..31 ascending, P1 = k 32..63 ascending.
    float p0 = 0.f, p1 = 0.f;
    if (isbf) {
        const __hip_bfloat16* w = (const __hip_bfloat16*)W2;
#pragma unroll
        for (int j = 0; j < 16; ++j) {
            p0 += __shfl(vx, j, 32) * b2f(w[(2 * j) * H2F + g]);
            p0 += __shfl(vy, j, 32) * b2f(w[(2 * j + 1) * H2F + g]);
        }
#pragma unroll
        for (int j = 16; j < 32; ++j) {
            p1 += __shfl(vx, j, 32) * b2f(w[(2 * j) * H2F + g]);
            p1 += __shfl(vy, j, 32) * b2f(w[(2 * j + 1) * H2F + g]);
        }
    } else {
        const float* w = (const float*)W2;
#pragma unroll
        for (int j = 0; j < 16; ++j) {
            p0 += __shfl(vx, j, 32) * w[(2 * j) * H2F + g];
            p0 += __shfl(vy, j, 32) * w[(2 * j + 1) * H2F + g];
        }
#pragma unroll
        for (int j = 16; j < 32; ++j) {
            p1 += __shfl(vx, j, 32) * w[(2 * j) * H2F + g];
            p1 += __shfl(vy, j, 32) * w[(2 * j + 1) * H2F + g];
        }
    }
    h2[(size_t)n * H2F + g] = f2us(p0 + p1);
}

// ---------------- fused agg2 + final MLP -> out ; QUARTER-WAVE (16 lanes) per node -----
// lane g holds features 2g,2g+1 of 32 (dword gathers). MLP chains k=0..31 sequential
// (j-loop issues k=2j then 2j+1) — matches original single-chain association exactly.
__global__ void __launch_bounds__(256)
GCN_51737176048479_kernel(const unsigned short* __restrict__ h2,
                          const float* __restrict__ dinv,
                          const int* __restrict__ rowptr,
                          const int* __restrict__ csr,
                          const void* __restrict__ b2v,
                          const void* __restrict__ Wf,
                          const void* __restrict__ bfv,
                          const void* __restrict__ Wo,
                          const void* __restrict__ bov,
                          void* __restrict__ out,
                          const int* __restrict__ flags) {
    int tid = blockIdx.x * blockDim.x + threadIdx.x;
    int n = tid >> 4;
    int g = threadIdx.x & 15;                           // feature pair index
    if (n >= N_NODES) return;
    int isbf = flags[1];
    int beg = rowptr[n], end = rowptr[n + 1];
    float dn = dinv[n];
    const unsigned* h2w = (const unsigned*)h2;
    unsigned su = h2w[(size_t)n * 16 + g];
    float ax = dn * lo2f(su);
    float ay = dn * hi2f(su);
    int e = beg;
    for (; e + 7 < end; e += 8) {
        int s0 = csr[e],     s1 = csr[e + 1], s2 = csr[e + 2], s3 = csr[e + 3];
        int s4 = csr[e + 4], s5 = csr[e + 5], s6 = csr[e + 6], s7 = csr[e + 7];
        float w0 = dinv[s0], w1 = dinv[s1], w2 = dinv[s2], w3 = dinv[s3];
        float w4 = dinv[s4], w5 = dinv[s5], w6 = dinv[s6], w7 = dinv[s7];
        unsigned u0 = h2w[(size_t)s0 * 16 + g];
        unsigned u1 = h2w[(size_t)s1 * 16 + g];
        unsigned u2 = h2w[(size_t)s2 * 16 + g];
        unsigned u3 = h2w[(size_t)s3 * 16 + g];
        unsigned u4 = h2w[(size_t)s4 * 16 + g];
        unsigned u5 = h2w[(size_t)s5 * 16 + g];
        unsigned u6 = h2w[(size_t)s6 * 16 + g];
        unsigned u7 = h2w[(size_t)s7 * 16 + g];
        ax += w0 * lo2f(u0); ay += w0 * hi2f(u0);
        ax += w1 * lo2f(u1); ay += w1 * hi2f(u1);
        ax += w2 * lo2f(u2); ay += w2 * hi2f(u2);
        ax += w3 * lo2f(u3); ay += w3 * hi2f(u3);
        ax += w4 * lo2f(u4); ay += w4 * hi2f(u4);
        ax += w5 * lo2f(u5); ay += w5 * hi2f(u5);
        ax += w6 * lo2f(u6); ay += w6 * hi2f(u6);
        ax += w7 * lo2f(u7); ay += w7 * hi2f(u7);
    }
    for (; e + 3 < end; e += 4) {
        int s0 = csr[e], s1 = csr[e + 1], s2 = csr[e + 2], s3 = csr[e + 3];
        float w0 = dinv[s0], w1 = dinv[s1], w2 = dinv[s2], w3 = dinv[s3];
        unsigned u0 = h2w[(size_t)s0 * 16 + g];
        unsigned u1 = h2w[(size_t)s1 * 16 + g];
        unsigned u2 = h2w[(size_t)s2 * 16 + g];
        unsigned u3 = h2w[(size_t)s3 * 16 + g];
        ax += w0 * lo2f(u0); ay += w0 * hi2f(u0);
        ax += w1 * lo2f(u1); ay += w1 * hi2f(u1);
        ax += w2 * lo2f(u2); ay += w2 * hi2f(u2);
        ax += w3 * lo2f(u3); ay += w3 * hi2f(u3);
    }
    for (; e < end; ++e) {
        int s = csr[e];
        float w = dinv[s];
        unsigned u = h2w[(size_t)s * 16 + g];
        ax += w * lo2f(u); ay += w * hi2f(u);
    }
    // conv2 out (no relu): features 2g, 2g+1
    ax = ax * dn + ld(b2v, 2 * g, isbf);
    ay = ay * dn + ld(b2v, 2 * g + 1, isbf);
    // MLP1: single chain k=0..31 ascending per output column (2g and 2g+1)
    float a1x = 0.f, a1y = 0.f;
#pragma unroll
    for (int j = 0; j < 16; ++j) {
        float fx = __shfl(ax, j, 16);                   // feature 2j
        float fy = __shfl(ay, j, 16);                   // feature 2j+1
        float wx0 = ld(Wf, (size_t)(2 * j) * H2F + 2 * g, isbf);
        float wx1 = ld(Wf, (size_t)(2 * j + 1) * H2F + 2 * g, isbf);
        float wy0 = ld(Wf, (size_t)(2 * j) * H2F + 2 * g + 1, isbf);
        float wy1 = ld(Wf, (size_t)(2 * j + 1) * H2F + 2 * g + 1, isbf);
        a1x += fx * wx0; a1x += fy * wx1;
        a1y += fx * wy0; a1y += fy * wy1;
    }
    float ux = fmaxf(a1x + ld(bfv, 2 * g, isbf), 0.f);
    float uy = fmaxf(a1y + ld(bfv, 2 * g + 1, isbf), 0.f);
    // MLP2: single chain k=0..31 ascending
    float a2x = 0.f, a2y = 0.f;
#pragma unroll
    for (int j = 0; j < 16; ++j) {
        float fx = __shfl(ux, j, 16);
        float fy = __shfl(uy, j, 16);
        float wx0 = ld(Wo, (size_t)(2 * j) * NCLS + 2 * g, isbf);
        float wx1 = ld(Wo, (size_t)(2 * j + 1) * NCLS + 2 * g, isbf);
        float wy0 = ld(Wo, (size_t)(2 * j) * NCLS + 2 * g + 1, isbf);
        float wy1 = ld(Wo, (size_t)(2 * j + 1) * NCLS + 2 * g + 1, isbf);
        a2x += fx * wx0; a2x += fy * wx1;
        a2y += fx * wy0; a2y += fy * wy1;
    }
    float rx = a2x + ld(bov, 2 * g, isbf);
    float ry = a2y + ld(bov, 2 * g + 1, isbf);
    if (isbf) {
        unsigned pack = (unsigned)f2us(rx) | ((unsigned)f2us(ry) << 16);
        ((unsigned*)out)[(size_t)n * 16 + g] = pack;
    } else {
        float2 r2 = make_float2(rx, ry);
        ((float2*)out)[(size_t)n * 16 + g] = r2;
    }
}

extern "C" void kernel_launch(void* const* d_in, const int* in_sizes, int n_in,
                              void* d_out, int out_size, void* d_ws, size_t ws_size,
                              hipStream_t stream) {
    const void* x  = d_in[0];
    const int*  ei = (const int*)d_in[1];
    const void* W1 = d_in[2];
    const void* b1 = d_in[3];
    const void* W2 = d_in[4];
    const void* b2 = d_in[5];
    const void* Wf = d_in[6];
    const void* bf = d_in[7];
    const void* Wo = d_in[8];
    const void* bo = d_in[9];

    // workspace (peak ~48 MB):
    //  deg @0 | rowptr @512K | dinv @1M | flags @1.4M | partial @1.41M
    //  aux @2M (12.8M) | csr @15M (12.8M) | h1 @28M (12.8M bf16) | h2 @41M (6.4M bf16)
    char* ws = (char*)d_ws;
    int*            deg      = (int*)  (ws + 0);
    int*            rowptr   = (int*)  (ws + (512u  << 10));
    float*          dinv     = (float*)(ws + (1024u << 10));
    int*            flags    = (int*)  (ws + (1434u << 10));
    int*            partial  = (int*)  (ws + (1444u << 10));
    int*            aux      = (int*)  (ws + (2u  << 20));
    int*            csr      = (int*)  (ws + (15u << 20));
    unsigned short* h1       = (unsigned short*)(ws + (28u << 20));
    unsigned short* h2       = (unsigned short*)(ws + (41u << 20));

    const int B = 256;

    k_init<<<SCAN_CHUNKS, SCAN_BLOCK, 0, stream>>>(x, ei, flags, deg);

    // fused gemm1 + histogram (independent work, interleaved for co-residency)
    k_front<<<NFRONT, B, 0, stream>>>(x, W1, ei, deg, aux, h1, flags);

    k_scanA<<<SCAN_CHUNKS, SCAN_BLOCK, 0, stream>>>(deg, partial, dinv);
    k_scanC<<<SCAN_CHUNKS, SCAN_BLOCK, 0, stream>>>(deg, partial, rowptr);
    k_scatter<<<(N_EDGES / 8 + B - 1) / B, B, 0, stream>>>(ei, aux, rowptr, csr, flags);

    k_agg1gemm2<<<(N_NODES * 32 + B - 1) / B, B, 0, stream>>>(h1, dinv, rowptr, csr,
                                                              b1, W2, h2, flags);
    GCN_51737176048479_kernel<<<(N_NODES * 16 + B - 1) / B, B, 0, stream>>>(
        h2, dinv, rowptr, csr, b2, Wf, bf, Wo, bo, d_out, flags);
}